// Round 9
// baseline (218.504 us; speedup 1.0000x reference)
//
#include <hip/hip_runtime.h>

// MFELoss: fused softmax(C=4) + masked-mean reduction to a scalar.
// R9: global_load_lds DMA probe. R6-R8 established a per-CU outstanding-
// read-line cap (~69 lines) -> ~2.7 TB/s read ceiling regardless of per-wave
// depth (R7) or lines/instr (R8). The DMA-to-LDS path is the only read
// mechanism that doesn't return through the wave's VGPR/vmcnt window; if the
// HW tracks it in deeper queues (like the 6.8 TB/s write path), this wins.
// Shape: 512 blocks x 1024 thr (2 blocks/CU), 8 tiles x 2048 rows per block,
// per tile: DMA 32KB preds + 8KB target -> LDS, sync, 2 rows/thread, sync.
// ~140 us of reported dur_us is fixed harness restore/poison overhead.

#define BLOCK 1024
#define TILE 2048           // rows per tile
#define NTILES 8            // 512 * 1024 * 16 rows = 2^23 exactly
#define GRID 512

typedef float vfloat4 __attribute__((ext_vector_type(4)));
typedef int   vint4   __attribute__((ext_vector_type(4)));

__device__ __forceinline__ void gl_lds16(const void* g, void* l) {
    __builtin_amdgcn_global_load_lds(
        (const __attribute__((address_space(1))) void*)g,
        (__attribute__((address_space(3))) void*)l, 16, 0, 0);
}

__device__ __forceinline__ void mfe_row(vfloat4 x, int t, int o,
                                        float& fne_acc, float& fpe_acc,
                                        float& cnt_acc) {
    float m = fmaxf(fmaxf(x.x, x.y), fmaxf(x.z, x.w));
    float e0 = __expf(x.x - m);
    float e1 = __expf(x.y - m);
    float e2 = __expf(x.z - m);
    float e3 = __expf(x.w - m);
    float S = (e0 + e1) + (e2 + e3);
    float r = 1.0f / S;
    float p0 = e0 * r, p1 = e1 * r, p2 = e2 * r, p3 = e3 * r;
    float s = ((p0 + p1) + p2) + p3;          // ~1.0, computed faithfully
    float po = (o == 0) ? p0 : (o == 1) ? p1 : (o == 2) ? p2 : p3;

    float d1 = s - po;
    float d2 = po - 1.0f;
    float fne_i = 0.5f * (d1 * d1 + d2 * d2);
    float fpe_i = po * po;                    // 0.5*(po^2+po^2)

    bool is_o = (t == o);
    fne_acc += is_o ? fne_i : 0.0f;
    fpe_acc += is_o ? 0.0f : fpe_i;
    cnt_acc += is_o ? 1.0f : 0.0f;            // exact in fp32 at these counts
}

__global__ __launch_bounds__(BLOCK) void mfe_partial(
    const vfloat4* __restrict__ preds,
    const int* __restrict__ target,
    const int* __restrict__ others_idx_p,
    float* __restrict__ fne_part,
    float* __restrict__ fpe_part,
    float* __restrict__ cnt_part,
    int n_rows)
{
    __shared__ vfloat4 xs[TILE];   // 32 KiB
    __shared__ int     ts[TILE];   //  8 KiB

    const int o = *others_idx_p;   // wave-uniform scalar
    const int tid  = threadIdx.x;
    const int wave = tid >> 6;
    const int lane = tid & 63;
    const int block_row0 = blockIdx.x * (TILE * NTILES);

    float fne_acc = 0.0f, fpe_acc = 0.0f, cnt_acc = 0.0f;

    for (int t = 0; t < NTILES; ++t) {
        const int row0 = block_row0 + t * TILE;

        // --- DMA issue phase: each wave moves 1 KiB per instr ---
        // preds: 32 KiB = 32 segments of 64 rows; wave w owns segs 2w, 2w+1
        {
            int seg = wave * 2;
            gl_lds16(preds + row0 + seg * 64 + lane, &xs[seg * 64]);
            gl_lds16(preds + row0 + (seg + 1) * 64 + lane, &xs[(seg + 1) * 64]);
            // target: 8 KiB = 8 segments of 1 KiB; waves 0..7 take one each
            if (wave < 8) {
                const vint4* gt = (const vint4*)(target + row0) + wave * 64 + lane;
                gl_lds16(gt, (int*)ts + wave * 256);
            }
        }
        __syncthreads();   // compiler inserts s_waitcnt vmcnt(0) before barrier

        // --- compute phase: 2 rows per thread from LDS ---
        {
            vfloat4 x0 = xs[tid];
            vfloat4 x1 = xs[tid + 1024];
            int t0 = ts[tid];
            int t1 = ts[tid + 1024];
            mfe_row(x0, t0, o, fne_acc, fpe_acc, cnt_acc);
            mfe_row(x1, t1, o, fne_acc, fpe_acc, cnt_acc);
        }
        __syncthreads();   // protect LDS before next tile's DMA overwrites
    }

    // 64-lane wave reduction
    #pragma unroll
    for (int off = 32; off > 0; off >>= 1) {
        fne_acc += __shfl_down(fne_acc, off, 64);
        fpe_acc += __shfl_down(fpe_acc, off, 64);
        cnt_acc += __shfl_down(cnt_acc, off, 64);
    }

    // per-wave partials: no extra LDS round-trip
    if (lane == 0) {
        int part = blockIdx.x * (BLOCK / 64) + wave;
        fne_part[part] = fne_acc;
        fpe_part[part] = fpe_acc;
        cnt_part[part] = cnt_acc;
    }
}

__global__ __launch_bounds__(1024) void mfe_final(
    const float* __restrict__ fne_part,
    const float* __restrict__ fpe_part,
    const float* __restrict__ cnt_part,
    int nparts, int n_rows, float* __restrict__ out)
{
    double fn = 0.0, fp = 0.0, c = 0.0;
    for (int i = threadIdx.x; i < nparts; i += blockDim.x) {
        fn += (double)fne_part[i];
        fp += (double)fpe_part[i];
        c  += (double)cnt_part[i];
    }
    #pragma unroll
    for (int off = 32; off > 0; off >>= 1) {
        fn += __shfl_down(fn, off, 64);
        fp += __shfl_down(fp, off, 64);
        c  += __shfl_down(c, off, 64);
    }
    __shared__ double s_fn[16], s_fp[16], s_c[16];
    int wave = threadIdx.x >> 6;
    int lane = threadIdx.x & 63;
    if (lane == 0) { s_fn[wave] = fn; s_fp[wave] = fp; s_c[wave] = c; }
    __syncthreads();

    if (threadIdx.x == 0) {
        double tfn = 0.0, tfp = 0.0, tc = 0.0;
        int nwaves = blockDim.x >> 6;
        for (int w = 0; w < nwaves; ++w) { tfn += s_fn[w]; tfp += s_fp[w]; tc += s_c[w]; }
        double fne_num = tc;
        double fpe_num = (double)n_rows - fne_num;
        double res = 0.0;
        if (fpe_num > 0.0) res += tfp / fpe_num;
        if (fne_num > 0.0) res += tfn / fne_num;
        out[0] = (float)res;
    }
}

extern "C" void kernel_launch(void* const* d_in, const int* in_sizes, int n_in,
                              void* d_out, int out_size, void* d_ws, size_t ws_size,
                              hipStream_t stream) {
    const vfloat4* preds = (const vfloat4*)d_in[0];
    const int* target = (const int*)d_in[1];
    const int* others_idx = (const int*)d_in[2];
    float* out = (float*)d_out;

    int n_rows = in_sizes[0] / 4;   // B = 8388608 = 512*1024*16 exactly

    int nparts = GRID * (BLOCK / 64);   // 8192 per-wave partials

    float* fne_part = (float*)d_ws;
    float* fpe_part = fne_part + nparts;
    float* cnt_part = fpe_part + nparts;

    mfe_partial<<<GRID, BLOCK, 0, stream>>>(preds, target, others_idx,
                                            fne_part, fpe_part, cnt_part, n_rows);
    mfe_final<<<1, 1024, 0, stream>>>(fne_part, fpe_part, cnt_part,
                                      nparts, n_rows, out);
}